// Round 7
// baseline (75.834 us; speedup 1.0000x reference)
//
#include <hip/hip_runtime.h>
#include <stdint.h>

typedef unsigned long long u64;

// Binarized MLP: every matmul is sign(x) @ sign(w)^T => XOR+popcount on
// bit-packed rows: dot = K - 2*popcount(xa ^ xw).
// Round 7: r1 champion geometry (512 thr = 1 col/thread, 32 rows/block,
// 512 blocks), but weights served from LDS (pair-interleaved u128,
// lane-consecutive => conflict-free b128 reads) instead of per-thread
// registers (r1/r3/r6: compiler refuses to keep 26 weight VGPRs live).
// Acts: packed Xp staged coalesced (r1-style; r4/r6 inline pack was a
// latency chain). ONE pack dispatch for x + all weights.

#define NB    16384
#define DIN   784
#define HID   512
#define DOUT  10
#define AST1  14        // L1 act words (13 real + 1 zero pad) -> u128 aligned
#define KP1   7         // L1 k-pairs
#define KP2   4         // L2/L3 k-pairs
#define RB    32
#define THR   512

// ws layout in u64:
//  W1L [7][512] u128  = u64[14336/...]: idx (kp*512+c)*2+(k&1)   [0,    7168)
//  W2L [4][512] u128:  base 7168                                  [7168, 11264)
//  W3L [4][512] u128:  base 11264                                 [11264,15360)
//  W4p [10][8]  u64:   base 15360                                 [15360,15440)
//  Xp  [16384][14] u64: base 15440 (word 13 = 0 pad)
#define W2B  7168
#define W3B  11264
#define W4B  15360
#define XPB  15440

// --------------- single pack dispatch: weights + x ---------------
// Pad bits are 0 on BOTH operands -> never mismatch in xor.
__global__ void bmlp_pack(const float* __restrict__ x,
                          const float* __restrict__ w1, const float* __restrict__ w2,
                          const float* __restrict__ w3, const float* __restrict__ w4,
                          u64* __restrict__ Wg)
{
    int gw   = (int)((blockIdx.x * blockDim.x + threadIdx.x) >> 6);
    int lane = threadIdx.x & 63;

    if (gw < HID * AST1) {                      // w1: 512 cols x 14 words
        int c = gw / AST1, k = gw - c * AST1;
        u64 word = 0;
        if (k < 13) {
            int e = k * 64 + lane;
            float v = (e < DIN) ? w1[c * DIN + e] : 1.0f;   // pad -> bit 0
            word = __ballot(v < 0.0f);
        }
        if (lane == 0) Wg[((k >> 1) * HID + c) * 2 + (k & 1)] = word;
        return;
    }
    gw -= HID * AST1;
    if (gw < HID * 8) {                         // w2: 512 cols x 8 words
        int c = gw >> 3, k = gw & 7;
        u64 word = __ballot(w2[c * HID + k * 64 + lane] < 0.0f);
        if (lane == 0) Wg[W2B + ((k >> 1) * HID + c) * 2 + (k & 1)] = word;
        return;
    }
    gw -= HID * 8;
    if (gw < HID * 8) {                         // w3
        int c = gw >> 3, k = gw & 7;
        u64 word = __ballot(w3[c * HID + k * 64 + lane] < 0.0f);
        if (lane == 0) Wg[W3B + ((k >> 1) * HID + c) * 2 + (k & 1)] = word;
        return;
    }
    gw -= HID * 8;
    if (gw < DOUT * 8) {                        // w4: [10][512] -> W4p[10][8]
        int c = gw >> 3, k = gw & 7;
        u64 word = __ballot(w4[c * HID + k * 64 + lane] < 0.0f);
        if (lane == 0) Wg[W4B + c * 8 + k] = word;
        return;
    }
    gw -= DOUT * 8;
    if (gw < NB * AST1) {                       // x: 16384 rows x 14 words
        int r = gw / AST1, k = gw - r * AST1;
        u64 word = 0;
        if (k < 13) {
            int e = k * 64 + lane;
            float v = (e < DIN) ? x[(size_t)r * DIN + e] : 1.0f;
            word = __ballot(v < 0.0f);
        }
        if (lane == 0) Wg[XPB + r * AST1 + k] = word;
    }
}

// One binarized layer, weights from LDS.
// act row read: b128 wave-broadcast (same addr all lanes, conflict-free).
// weight read:  Wl2[kp*512 + j], lane-consecutive u128 -> conflict-free.
// BN epilogue exact reference op order (proven r1-r6, absmax=0):
//   A = g*(1/sqrt(v+eps)); y = ((dot+b)-m)*A + be; sign -> ballot word.
template<int KP, int ASTR>
__device__ __forceinline__ void bin_layer(
    const u64* act, u64* actOut, const ulonglong2* Wl2,
    const float* __restrict__ b, const float* __restrict__ g,
    const float* __restrict__ be, const float* __restrict__ m,
    const float* __restrict__ v, float eps, int K)
{
    const int j = threadIdx.x, w = j >> 6, lane = j & 63;

    const float pb = b[j], pm = m[j], pe = be[j];
    const float pA = __fmul_rn(g[j], __fdiv_rn(1.0f, __fsqrt_rn(__fadd_rn(v[j], eps))));

#pragma unroll 4
    for (int r = 0; r < RB; ++r) {
        const u64* row = act + r * ASTR;
        int c0 = 0, c1 = 0;
#pragma unroll
        for (int kp = 0; kp < KP; ++kp) {
            ulonglong2 a  = *reinterpret_cast<const ulonglong2*>(row + 2 * kp);
            ulonglong2 wv = Wl2[kp * HID + j];
            c0 += (int)__popcll(a.x ^ wv.x);
            c1 += (int)__popcll(a.y ^ wv.y);
        }
        float dotf = (float)(K - 2 * (c0 + c1));        // exact integer
        float xl = __fadd_rn(dotf, pb);
        float y  = __fadd_rn(__fmul_rn(__fsub_rn(xl, pm), pA), pe);
        u64 bal = __ballot(y < 0.0f);                   // bit=1 <=> -1
        if (lane == 0) actOut[r * 8 + w] = bal;         // word w of row r
    }
}

__global__ __launch_bounds__(THR)
void bmlp_fused(const u64* __restrict__ Wg,
                const float* __restrict__ b1, const float* __restrict__ g1,
                const float* __restrict__ be1, const float* __restrict__ m1,
                const float* __restrict__ v1,
                const float* __restrict__ b2, const float* __restrict__ g2,
                const float* __restrict__ be2, const float* __restrict__ m2,
                const float* __restrict__ v2,
                const float* __restrict__ b3, const float* __restrict__ g3,
                const float* __restrict__ be3, const float* __restrict__ m3,
                const float* __restrict__ v3,
                const float* __restrict__ b4,
                float* __restrict__ out)
{
    __shared__ __align__(16) u64 Wl[KP1 * HID * 2];     // 57344 B
    __shared__ __align__(16) u64 A1[RB * AST1];         // 3584 B
    __shared__ __align__(16) u64 A2[RB * 8];            // 2048 B
    __shared__ __align__(16) u64 A3[RB * 8];            // 2048 B => 65024 total
    const int t = threadIdx.x;
    const int row0 = blockIdx.x * RB;

    ulonglong2* Wl2 = reinterpret_cast<ulonglong2*>(Wl);
    const ulonglong2* Wg2 = reinterpret_cast<const ulonglong2*>(Wg);

    // stage W1 (3584 u128, 7/thread) + acts (224 u128), all coalesced
#pragma unroll
    for (int i = 0; i < KP1; ++i) Wl2[t + i * HID] = Wg2[t + i * HID];
    if (t < RB * AST1 / 2)
        reinterpret_cast<ulonglong2*>(A1)[t] =
            reinterpret_cast<const ulonglong2*>(Wg + XPB + row0 * AST1)[t];
    __syncthreads();

    bin_layer<KP1, AST1>(A1, A2, Wl2, b1, g1, be1, m1, v1, 1e-5f, DIN);
    __syncthreads();

#pragma unroll
    for (int i = 0; i < KP2; ++i) Wl2[t + i * HID] = Wg2[W2B / 2 + t + i * HID];
    __syncthreads();
    bin_layer<KP2, 8>(A2, A3, Wl2, b2, g2, be2, m2, v2, 1e-5f, HID);
    __syncthreads();

#pragma unroll
    for (int i = 0; i < KP2; ++i) Wl2[t + i * HID] = Wg2[W3B / 2 + t + i * HID];
    __syncthreads();
    bin_layer<KP2, 8>(A3, A2, Wl2, b3, g3, be3, m3, v3, 512.0f, HID); // EPS3 bug
    __syncthreads();

    // L4: out = dot + b4. r = t>>4 (32 rows), c = t&15 (10 used).
    {
        int r = t >> 4, c = t & 15;
        if (c < DOUT) {
            const u64* arow = A2 + r * 8;
            const u64* w4r  = Wg + W4B + c * 8;
            int mm = 0;
#pragma unroll
            for (int k = 0; k < 8; ++k)
                mm += (int)__popcll(arow[k] ^ w4r[k]);
            out[(size_t)(row0 + r) * DOUT + c] =
                __fadd_rn((float)(HID - 2 * mm), b4[c]);
        }
    }
}

extern "C" void kernel_launch(void* const* d_in, const int* in_sizes, int n_in,
                              void* d_out, int out_size, void* d_ws, size_t ws_size,
                              hipStream_t stream)
{
    const float* x   = (const float*)d_in[0];
    const float* w1  = (const float*)d_in[1];
    const float* b1  = (const float*)d_in[2];
    const float* g1  = (const float*)d_in[3];
    const float* be1 = (const float*)d_in[4];
    const float* m1  = (const float*)d_in[5];
    const float* v1  = (const float*)d_in[6];
    const float* w2  = (const float*)d_in[7];
    const float* b2  = (const float*)d_in[8];
    const float* g2  = (const float*)d_in[9];
    const float* be2 = (const float*)d_in[10];
    const float* m2  = (const float*)d_in[11];
    const float* v2  = (const float*)d_in[12];
    const float* w3  = (const float*)d_in[13];
    const float* b3  = (const float*)d_in[14];
    const float* g3  = (const float*)d_in[15];
    const float* be3 = (const float*)d_in[16];
    const float* m3  = (const float*)d_in[17];
    const float* v3  = (const float*)d_in[18];
    const float* w4  = (const float*)d_in[19];
    const float* b4  = (const float*)d_in[20];
    float* out = (float*)d_out;

    u64* Wg = (u64*)d_ws;   // 15440 + 16384*14 u64 = 1.96 MB

    // waves: 512*14 + 512*8 + 512*8 + 80 + 16384*14 = 244816 -> /4 blocks
    const int packWaves = HID * AST1 + 2 * HID * 8 + DOUT * 8 + NB * AST1;
    bmlp_pack<<<dim3((packWaves + 3) / 4), 256, 0, stream>>>(
        x, w1, w2, w3, w4, Wg);

    bmlp_fused<<<dim3(NB / RB), THR, 0, stream>>>(
        Wg,
        b1, g1, be1, m1, v1,
        b2, g2, be2, m2, v2,
        b3, g3, be3, m3, v3,
        b4, out);
}

// Round 8
// 58.174 us; speedup vs baseline: 1.3036x; 1.3036x over previous
//
#include <hip/hip_runtime.h>
#include <stdint.h>

typedef unsigned long long u64;

// Binarized MLP: every matmul is sign(x) @ sign(w)^T => XOR+popcount on
// bit-packed rows: dot = K - 2*popcount(xa ^ xw).
// Round 8: 4 rows x 8 cols register tile per thread (cnt[4][8]) so each LDS
// read feeds 21x more VALU than r1/r7 (which re-read every weight word per
// row: LDS-issue-bound at ~38us/CU). Weights staged in LDS per layer
// (r7 machinery); acts wave-private (wave packs its own 4 x-rows inline,
// 13-wide unrolled ILP); BN scale A precomputed bit-exactly in pack_w.
// x-pack dispatch eliminated.

#define NB    16384
#define DIN   784
#define HID   512
#define DOUT  10
#define AST1  14        // L1 act row words (13 real + 1 zero pad)
#define KP1   7         // L1 k-pairs
#define KP2   4         // L2/L3 k-pairs
#define RB    32        // rows per block (8 waves x 4 rows)

// ws layout (u64):
//  W1L [7][512] u128 pair-interleaved: u64 idx ((k>>1)*512+c)*2+(k&1)  [0,7168)
//  W2L [4][512] u128: base 7168        W3L: base 11264
//  W4p [10][8] u64:   base 15360
//  Apre[3][512] f32:  base 15440 (bit-exact g*rsqrt(v+eps) per layer)
#define W2B  7168
#define W3B  11264
#define W4B  15360
#define APB  15440

// --------------- weight pack + BN-scale precompute (tiny) ---------------
__global__ void bmlp_pack(const float* __restrict__ w1, const float* __restrict__ w2,
                          const float* __restrict__ w3, const float* __restrict__ w4,
                          const float* __restrict__ g1, const float* __restrict__ v1,
                          const float* __restrict__ g2, const float* __restrict__ v2,
                          const float* __restrict__ g3, const float* __restrict__ v3,
                          u64* __restrict__ Wg)
{
    int gw   = (int)((blockIdx.x * blockDim.x + threadIdx.x) >> 6);
    int lane = threadIdx.x & 63;

    if (gw < HID * AST1) {                      // w1: 512 cols x 14 words
        int c = gw / AST1, k = gw - c * AST1;
        u64 word = 0;
        if (k < 13) {
            int e = k * 64 + lane;
            float v = (e < DIN) ? w1[c * DIN + e] : 1.0f;   // pad -> bit 0
            word = __ballot(v < 0.0f);
        }
        if (lane == 0) Wg[((k >> 1) * HID + c) * 2 + (k & 1)] = word;
        return;
    }
    gw -= HID * AST1;
    if (gw < HID * 8) {                         // w2
        int c = gw >> 3, k = gw & 7;
        u64 word = __ballot(w2[c * HID + k * 64 + lane] < 0.0f);
        if (lane == 0) Wg[W2B + ((k >> 1) * HID + c) * 2 + (k & 1)] = word;
        return;
    }
    gw -= HID * 8;
    if (gw < HID * 8) {                         // w3
        int c = gw >> 3, k = gw & 7;
        u64 word = __ballot(w3[c * HID + k * 64 + lane] < 0.0f);
        if (lane == 0) Wg[W3B + ((k >> 1) * HID + c) * 2 + (k & 1)] = word;
        return;
    }
    gw -= HID * 8;
    if (gw < DOUT * 8) {                        // w4 row-packed
        int c = gw >> 3, k = gw & 7;
        u64 word = __ballot(w4[c * HID + k * 64 + lane] < 0.0f);
        if (lane == 0) Wg[W4B + c * 8 + k] = word;
        return;
    }
    gw -= DOUT * 8;
    if (gw < 24) {                              // A = g*(1/sqrt(v+eps)), exact
        int idx = gw * 64 + lane;               // 1536 cols total
        int ly = idx >> 9, c = idx & 511;
        const float* g = (ly == 0) ? g1 : (ly == 1) ? g2 : g3;
        const float* v = (ly == 0) ? v1 : (ly == 1) ? v2 : v3;
        float eps = (ly == 2) ? 512.0f : 1e-5f; // EPS3 source bug: 512
        float A = __fmul_rn(g[c], __fdiv_rn(1.0f, __fsqrt_rn(__fadd_rn(v[c], eps))));
        reinterpret_cast<float*>(Wg + APB)[idx] = A;
    }
}

// One binarized layer, 4x8 tile. Weight reads lane-consecutive u128
// (conflict-free); act reads wave-broadcast u128 (free). BN epilogue in
// exact reference op order (proven r1-r7, absmax=0):
//   y = ((dot + b) - m) * A + be ; sign -> ballot word.
// Lane L keeps word (r=L>>3, c=L&7); lanes<32 write the wave's 32 words.
template<int KP, int ASTR>
__device__ __forceinline__ void bin_layer(
    const u64* actIn, u64* actOut, const ulonglong2* Wl2,
    const float* __restrict__ b, const float* __restrict__ m,
    const float* __restrict__ be, const float* __restrict__ Ap,
    int K, int lane)
{
    int cnt[4][8];
#pragma unroll
    for (int r = 0; r < 4; ++r)
#pragma unroll
        for (int c = 0; c < 8; ++c) cnt[r][c] = 0;

#pragma unroll 1
    for (int kp = 0; kp < KP; ++kp) {
        ulonglong2 wv[8];
#pragma unroll
        for (int c = 0; c < 8; ++c)
            wv[c] = Wl2[kp * HID + c * 64 + lane];      // 1KB/wave, conflict-free
#pragma unroll
        for (int r = 0; r < 4; ++r) {
            ulonglong2 a = *reinterpret_cast<const ulonglong2*>(actIn + r * ASTR + 2 * kp);
#pragma unroll
            for (int c = 0; c < 8; ++c) {
                cnt[r][c] += (int)__popcll(a.x ^ wv[c].x);
                cnt[r][c] += (int)__popcll(a.y ^ wv[c].y);
            }
        }
    }

    float pb[8], pm[8], pe[8], pA[8];
#pragma unroll
    for (int c = 0; c < 8; ++c) {
        int col = c * 64 + lane;
        pb[c] = b[col]; pm[c] = m[col]; pe[c] = be[col]; pA[c] = Ap[col];
    }
    u64 myw = 0;
#pragma unroll
    for (int r = 0; r < 4; ++r)
#pragma unroll
        for (int c = 0; c < 8; ++c) {
            float dotf = (float)(K - 2 * cnt[r][c]);    // exact integer
            float xl = __fadd_rn(dotf, pb[c]);
            float y  = __fadd_rn(__fmul_rn(__fsub_rn(xl, pm[c]), pA[c]), pe[c]);
            u64 bal = __ballot(y < 0.0f);               // bit=1 <=> -1
            myw = (lane == r * 8 + c) ? bal : myw;
        }
    if (lane < 32) actOut[lane] = myw;                  // = actOut[r*8+c]
}

__global__ __launch_bounds__(512)
void bmlp_fused(const float* __restrict__ x, const u64* __restrict__ Wg,
                const float* __restrict__ b1, const float* __restrict__ m1,
                const float* __restrict__ be1,
                const float* __restrict__ b2, const float* __restrict__ m2,
                const float* __restrict__ be2,
                const float* __restrict__ b3, const float* __restrict__ m3,
                const float* __restrict__ be3,
                const float* __restrict__ b4,
                float* __restrict__ out)
{
    __shared__ __align__(16) u64 Wl[KP1 * HID * 2];     // 57344 B
    __shared__ __align__(16) u64 Acts[8 * 120];         // 7680 B => 65024 total
    const int t = threadIdx.x, w = t >> 6, lane = t & 63;
    const int row0 = blockIdx.x * RB + w * 4;           // wave-private rows

    u64* A1w = Acts + w * 120;                          // [4][14]
    u64* A2w = A1w + 56;                                // [4][8]
    u64* A3w = A2w + 32;                                // [4][8]
    ulonglong2* Wl2 = reinterpret_cast<ulonglong2*>(Wl);
    const ulonglong2* Wg2 = reinterpret_cast<const ulonglong2*>(Wg);
    const float* Ap = reinterpret_cast<const float*>(Wg + APB);

    // stage W1 (3584 u128, coalesced) -- overlaps with x-pack below
#pragma unroll
    for (int i = 0; i < KP1; ++i) Wl2[i * HID + t] = Wg2[i * HID + t];

    // pack my wave's 4 x-rows; 13-wide unrolled loads for ILP, ballot to
    // wave-private LDS (no barrier needed for acts, ever)
#pragma unroll 1
    for (int r = 0; r < 4; ++r) {
        const float* xr = x + (size_t)(row0 + r) * DIN;
        float vx[13];
#pragma unroll
        for (int k = 0; k < 13; ++k) {
            int e = k * 64 + lane;
            vx[k] = (e < DIN) ? xr[e] : 1.0f;           // pad -> bit 0
        }
#pragma unroll
        for (int k = 0; k < 13; ++k) {
            u64 word = __ballot(vx[k] < 0.0f);
            if (lane == 0) A1w[r * AST1 + k] = word;
        }
        if (lane == 0) A1w[r * AST1 + 13] = 0;          // zero pad word
    }
    __syncthreads();                                    // W1 staged

    bin_layer<KP1, AST1>(A1w, A2w, Wl2, b1, m1, be1, Ap, DIN, lane);
    __syncthreads();                                    // all done with W1
#pragma unroll
    for (int i = 0; i < KP2; ++i) Wl2[i * HID + t] = Wg2[W2B / 2 + i * HID + t];
    __syncthreads();
    bin_layer<KP2, 8>(A2w, A3w, Wl2, b2, m2, be2, Ap + 512, HID, lane);
    __syncthreads();
#pragma unroll
    for (int i = 0; i < KP2; ++i) Wl2[i * HID + t] = Wg2[W3B / 2 + i * HID + t];
    __syncthreads();
    bin_layer<KP2, 8>(A3w, A2w, Wl2, b3, m3, be3, Ap + 1024, HID, lane);

    // L4: out = dot + b4 (wave-private acts; W4 from global, L2/L3-hot)
    {
        int r = lane >> 4, c = lane & 15;
        if (c < DOUT) {
            const u64* arow = A2w + r * 8;
            const u64* w4r  = Wg + W4B + c * 8;
            int mm = 0;
#pragma unroll
            for (int k = 0; k < 8; ++k)
                mm += (int)__popcll(arow[k] ^ w4r[k]);
            out[(size_t)(row0 + r) * DOUT + c] =
                __fadd_rn((float)(HID - 2 * mm), b4[c]);
        }
    }
}

extern "C" void kernel_launch(void* const* d_in, const int* in_sizes, int n_in,
                              void* d_out, int out_size, void* d_ws, size_t ws_size,
                              hipStream_t stream)
{
    const float* x   = (const float*)d_in[0];
    const float* w1  = (const float*)d_in[1];
    const float* b1  = (const float*)d_in[2];
    const float* g1  = (const float*)d_in[3];
    const float* be1 = (const float*)d_in[4];
    const float* m1  = (const float*)d_in[5];
    const float* v1  = (const float*)d_in[6];
    const float* w2  = (const float*)d_in[7];
    const float* b2  = (const float*)d_in[8];
    const float* g2  = (const float*)d_in[9];
    const float* be2 = (const float*)d_in[10];
    const float* m2  = (const float*)d_in[11];
    const float* v2  = (const float*)d_in[12];
    const float* w3  = (const float*)d_in[13];
    const float* b3  = (const float*)d_in[14];
    const float* g3  = (const float*)d_in[15];
    const float* be3 = (const float*)d_in[16];
    const float* m3  = (const float*)d_in[17];
    const float* v3  = (const float*)d_in[18];
    const float* w4  = (const float*)d_in[19];
    const float* b4  = (const float*)d_in[20];
    float* out = (float*)d_out;

    u64* Wg = (u64*)d_ws;   // 15440 u64 + 1536 f32 = ~130 KB

    // waves: 512*14 + 512*8 + 512*8 + 80 + 24 = 15464 -> 3866 blocks of 256
    const int packWaves = HID * AST1 + 2 * HID * 8 + DOUT * 8 + 24;
    bmlp_pack<<<dim3((packWaves * 64 + 255) / 256), 256, 0, stream>>>(
        w1, w2, w3, w4, g1, v1, g2, v2, g3, v3, Wg);

    bmlp_fused<<<dim3(NB / RB), 512, 0, stream>>>(
        x, Wg,
        b1, m1, be1,
        b2, m2, be2,
        b3, m3, be3,
        b4, out);
}

// Round 9
// 58.145 us; speedup vs baseline: 1.3042x; 1.0005x over previous
//
#include <hip/hip_runtime.h>
#include <stdint.h>

typedef unsigned long long u64;

// Binarized MLP: every matmul is sign(x) @ sign(w)^T => XOR+popcount on
// bit-packed rows: dot = K - 2*popcount(xa ^ xw).
// Round 9: r8 structure + __launch_bounds__(512, 4). r1/r7/r8 all showed
// VGPR_Count <= 52: the backend's default occupancy target (8 waves/EU =>
// <=64 VGPR) forces operand parking (AGPR shuffles / LDS re-reads) for any
// register tile. LDS (63.5KB) caps us at 2 blocks/CU = 4 waves/EU anyway,
// so declare it: VGPR budget 512/4 = 128 — room for cnt[4][8]+wv[8] (~85).

#define NB    16384
#define DIN   784
#define HID   512
#define DOUT  10
#define AST1  14        // L1 act row words (13 real + 1 zero pad)
#define KP1   7         // L1 k-pairs
#define KP2   4         // L2/L3 k-pairs
#define RB    32        // rows per block (8 waves x 4 rows)

// ws layout (u64):
//  W1L [7][512] u128 pair-interleaved: u64 idx ((k>>1)*512+c)*2+(k&1)  [0,7168)
//  W2L [4][512] u128: base 7168        W3L: base 11264
//  W4p [10][8] u64:   base 15360
//  Apre[3][512] f32:  base 15440 (bit-exact g*rsqrt(v+eps) per layer)
#define W2B  7168
#define W3B  11264
#define W4B  15360
#define APB  15440

// --------------- weight pack + BN-scale precompute (tiny) ---------------
__global__ void bmlp_pack(const float* __restrict__ w1, const float* __restrict__ w2,
                          const float* __restrict__ w3, const float* __restrict__ w4,
                          const float* __restrict__ g1, const float* __restrict__ v1,
                          const float* __restrict__ g2, const float* __restrict__ v2,
                          const float* __restrict__ g3, const float* __restrict__ v3,
                          u64* __restrict__ Wg)
{
    int gw   = (int)((blockIdx.x * blockDim.x + threadIdx.x) >> 6);
    int lane = threadIdx.x & 63;

    if (gw < HID * AST1) {                      // w1: 512 cols x 14 words
        int c = gw / AST1, k = gw - c * AST1;
        u64 word = 0;
        if (k < 13) {
            int e = k * 64 + lane;
            float v = (e < DIN) ? w1[c * DIN + e] : 1.0f;   // pad -> bit 0
            word = __ballot(v < 0.0f);
        }
        if (lane == 0) Wg[((k >> 1) * HID + c) * 2 + (k & 1)] = word;
        return;
    }
    gw -= HID * AST1;
    if (gw < HID * 8) {                         // w2
        int c = gw >> 3, k = gw & 7;
        u64 word = __ballot(w2[c * HID + k * 64 + lane] < 0.0f);
        if (lane == 0) Wg[W2B + ((k >> 1) * HID + c) * 2 + (k & 1)] = word;
        return;
    }
    gw -= HID * 8;
    if (gw < HID * 8) {                         // w3
        int c = gw >> 3, k = gw & 7;
        u64 word = __ballot(w3[c * HID + k * 64 + lane] < 0.0f);
        if (lane == 0) Wg[W3B + ((k >> 1) * HID + c) * 2 + (k & 1)] = word;
        return;
    }
    gw -= HID * 8;
    if (gw < DOUT * 8) {                        // w4 row-packed
        int c = gw >> 3, k = gw & 7;
        u64 word = __ballot(w4[c * HID + k * 64 + lane] < 0.0f);
        if (lane == 0) Wg[W4B + c * 8 + k] = word;
        return;
    }
    gw -= DOUT * 8;
    if (gw < 24) {                              // A = g*(1/sqrt(v+eps)), exact
        int idx = gw * 64 + lane;               // 1536 cols total
        int ly = idx >> 9, c = idx & 511;
        const float* g = (ly == 0) ? g1 : (ly == 1) ? g2 : g3;
        const float* v = (ly == 0) ? v1 : (ly == 1) ? v2 : v3;
        float eps = (ly == 2) ? 512.0f : 1e-5f; // EPS3 source bug: 512
        float A = __fmul_rn(g[c], __fdiv_rn(1.0f, __fsqrt_rn(__fadd_rn(v[c], eps))));
        reinterpret_cast<float*>(Wg + APB)[idx] = A;
    }
}

// One binarized layer, 4x8 tile. Weight reads lane-consecutive u128
// (conflict-free); act reads wave-broadcast u128 (free). BN epilogue in
// exact reference op order (proven r1-r8, absmax=0):
//   y = ((dot + b) - m) * A + be ; sign -> ballot word.
// Lane L keeps word (r=L>>3, c=L&7); lanes<32 write the wave's 32 words.
template<int KP, int ASTR>
__device__ __forceinline__ void bin_layer(
    const u64* actIn, u64* actOut, const ulonglong2* Wl2,
    const float* __restrict__ b, const float* __restrict__ m,
    const float* __restrict__ be, const float* __restrict__ Ap,
    int K, int lane)
{
    int cnt[4][8];
#pragma unroll
    for (int r = 0; r < 4; ++r)
#pragma unroll
        for (int c = 0; c < 8; ++c) cnt[r][c] = 0;

#pragma unroll 1
    for (int kp = 0; kp < KP; ++kp) {
        ulonglong2 wv[8];
#pragma unroll
        for (int c = 0; c < 8; ++c)
            wv[c] = Wl2[kp * HID + c * 64 + lane];      // 1KB/wave, conflict-free
#pragma unroll
        for (int r = 0; r < 4; ++r) {
            ulonglong2 a = *reinterpret_cast<const ulonglong2*>(actIn + r * ASTR + 2 * kp);
#pragma unroll
            for (int c = 0; c < 8; ++c) {
                cnt[r][c] += (int)__popcll(a.x ^ wv[c].x);
                cnt[r][c] += (int)__popcll(a.y ^ wv[c].y);
            }
        }
    }

    float pb[8], pm[8], pe[8], pA[8];
#pragma unroll
    for (int c = 0; c < 8; ++c) {
        int col = c * 64 + lane;
        pb[c] = b[col]; pm[c] = m[col]; pe[c] = be[col]; pA[c] = Ap[col];
    }
    u64 myw = 0;
#pragma unroll
    for (int r = 0; r < 4; ++r)
#pragma unroll
        for (int c = 0; c < 8; ++c) {
            float dotf = (float)(K - 2 * cnt[r][c]);    // exact integer
            float xl = __fadd_rn(dotf, pb[c]);
            float y  = __fadd_rn(__fmul_rn(__fsub_rn(xl, pm[c]), pA[c]), pe[c]);
            u64 bal = __ballot(y < 0.0f);               // bit=1 <=> -1
            myw = (lane == r * 8 + c) ? bal : myw;
        }
    if (lane < 32) actOut[lane] = myw;                  // = actOut[r*8+c]
}

__global__ __launch_bounds__(512, 4)   // 4 waves/EU min => 128 VGPR budget
void bmlp_fused(const float* __restrict__ x, const u64* __restrict__ Wg,
                const float* __restrict__ b1, const float* __restrict__ m1,
                const float* __restrict__ be1,
                const float* __restrict__ b2, const float* __restrict__ m2,
                const float* __restrict__ be2,
                const float* __restrict__ b3, const float* __restrict__ m3,
                const float* __restrict__ be3,
                const float* __restrict__ b4,
                float* __restrict__ out)
{
    __shared__ __align__(16) u64 Wl[KP1 * HID * 2];     // 57344 B
    __shared__ __align__(16) u64 Acts[8 * 120];         // 7680 B => 65024 total
    const int t = threadIdx.x, w = t >> 6, lane = t & 63;
    const int row0 = blockIdx.x * RB + w * 4;           // wave-private rows

    u64* A1w = Acts + w * 120;                          // [4][14]
    u64* A2w = A1w + 56;                                // [4][8]
    u64* A3w = A2w + 32;                                // [4][8]
    ulonglong2* Wl2 = reinterpret_cast<ulonglong2*>(Wl);
    const ulonglong2* Wg2 = reinterpret_cast<const ulonglong2*>(Wg);
    const float* Ap = reinterpret_cast<const float*>(Wg + APB);

    // stage W1 (3584 u128, coalesced) -- overlaps with x-pack below
#pragma unroll
    for (int i = 0; i < KP1; ++i) Wl2[i * HID + t] = Wg2[i * HID + t];

    // pack my wave's 4 x-rows; 13-wide unrolled loads for ILP, ballot to
    // wave-private LDS (no barrier needed for acts, ever)
#pragma unroll 1
    for (int r = 0; r < 4; ++r) {
        const float* xr = x + (size_t)(row0 + r) * DIN;
        float vx[13];
#pragma unroll
        for (int k = 0; k < 13; ++k) {
            int e = k * 64 + lane;
            vx[k] = (e < DIN) ? xr[e] : 1.0f;           // pad -> bit 0
        }
#pragma unroll
        for (int k = 0; k < 13; ++k) {
            u64 word = __ballot(vx[k] < 0.0f);
            if (lane == 0) A1w[r * AST1 + k] = word;
        }
        if (lane == 0) A1w[r * AST1 + 13] = 0;          // zero pad word
    }
    __syncthreads();                                    // W1 staged

    bin_layer<KP1, AST1>(A1w, A2w, Wl2, b1, m1, be1, Ap, DIN, lane);
    __syncthreads();                                    // all done with W1
#pragma unroll
    for (int i = 0; i < KP2; ++i) Wl2[i * HID + t] = Wg2[W2B / 2 + i * HID + t];
    __syncthreads();
    bin_layer<KP2, 8>(A2w, A3w, Wl2, b2, m2, be2, Ap + 512, HID, lane);
    __syncthreads();
#pragma unroll
    for (int i = 0; i < KP2; ++i) Wl2[i * HID + t] = Wg2[W3B / 2 + i * HID + t];
    __syncthreads();
    bin_layer<KP2, 8>(A3w, A2w, Wl2, b3, m3, be3, Ap + 1024, HID, lane);

    // L4: out = dot + b4 (wave-private acts; W4 from global, L2/L3-hot)
    {
        int r = lane >> 4, c = lane & 15;
        if (c < DOUT) {
            const u64* arow = A2w + r * 8;
            const u64* w4r  = Wg + W4B + c * 8;
            int mm = 0;
#pragma unroll
            for (int k = 0; k < 8; ++k)
                mm += (int)__popcll(arow[k] ^ w4r[k]);
            out[(size_t)(row0 + r) * DOUT + c] =
                __fadd_rn((float)(HID - 2 * mm), b4[c]);
        }
    }
}

extern "C" void kernel_launch(void* const* d_in, const int* in_sizes, int n_in,
                              void* d_out, int out_size, void* d_ws, size_t ws_size,
                              hipStream_t stream)
{
    const float* x   = (const float*)d_in[0];
    const float* w1  = (const float*)d_in[1];
    const float* b1  = (const float*)d_in[2];
    const float* g1  = (const float*)d_in[3];
    const float* be1 = (const float*)d_in[4];
    const float* m1  = (const float*)d_in[5];
    const float* v1  = (const float*)d_in[6];
    const float* w2  = (const float*)d_in[7];
    const float* b2  = (const float*)d_in[8];
    const float* g2  = (const float*)d_in[9];
    const float* be2 = (const float*)d_in[10];
    const float* m2  = (const float*)d_in[11];
    const float* v2  = (const float*)d_in[12];
    const float* w3  = (const float*)d_in[13];
    const float* b3  = (const float*)d_in[14];
    const float* g3  = (const float*)d_in[15];
    const float* be3 = (const float*)d_in[16];
    const float* m3  = (const float*)d_in[17];
    const float* v3  = (const float*)d_in[18];
    const float* w4  = (const float*)d_in[19];
    const float* b4  = (const float*)d_in[20];
    float* out = (float*)d_out;

    u64* Wg = (u64*)d_ws;   // 15440 u64 + 1536 f32 = ~130 KB

    // waves: 512*14 + 512*8 + 512*8 + 80 + 24 = 15464 -> 3866 blocks of 256
    const int packWaves = HID * AST1 + 2 * HID * 8 + DOUT * 8 + 24;
    bmlp_pack<<<dim3((packWaves * 64 + 255) / 256), 256, 0, stream>>>(
        w1, w2, w3, w4, g1, v1, g2, v2, g3, v3, Wg);

    bmlp_fused<<<dim3(NB / RB), 512, 0, stream>>>(
        x, Wg,
        b1, m1, be1,
        b2, m2, be2,
        b3, m3, be3,
        b4, out);
}